// Round 16
// baseline (673.475 us; speedup 1.0000x reference)
//
#include <hip/hip_runtime.h>
#include <hip/hip_bf16.h>

typedef _Float16 f16;
typedef _Float16 f16x4 __attribute__((ext_vector_type(4)));
typedef _Float16 f16x8 __attribute__((ext_vector_type(8)));
typedef float f32x4 __attribute__((ext_vector_type(4)));

__device__ __forceinline__ void gload16(const void* g, void* l) {
    __builtin_amdgcn_global_load_lds(
        (const __attribute__((address_space(1))) void*)g,
        (__attribute__((address_space(3))) void*)l, 16, 0, 0);
}

#define FENCE asm volatile("" ::: "memory")
#define BARRIER do { FENCE; __builtin_amdgcn_s_barrier(); FENCE; } while (0)

// ===========================================================================
// 8-phase 256x256 BT-GEMM core, r16: counted-vmcnt pipeline (T4).
// Per tile g: ph1 issues A(g+1) then vmcnt(4) -> waits ONLY tile-g's loads
// (issued >=3 phases earlier, already landed), keeps A(g+1) in flight across
// the barrier; ph2 issues B(g+1). Never vmcnt(0) in steady state.
// ===========================================================================
#define PHASE_MFMA(QI, QJ)                                                    \
    __builtin_amdgcn_s_setprio(1);                                            \
    _Pragma("unroll")                                                         \
    for (int ks = 0; ks < 2; ++ks)                                            \
      _Pragma("unroll")                                                       \
      for (int i = 0; i < 4; ++i)                                             \
        _Pragma("unroll")                                                     \
        for (int j = 0; j < 2; ++j)                                           \
          acc[(QI)*4 + i][(QJ)*2 + j] = __builtin_amdgcn_mfma_f32_16x16x32_f16( \
              a[i][ks], b[j][ks], acc[(QI)*4 + i][(QJ)*2 + j], 0, 0, 0);      \
    __builtin_amdgcn_s_setprio(0);

#define BT8_BODY(KBASE, NTILES)                                               \
    const int rr8 = lane >> 3;                                                \
    const int cs  = ((lane & 7) ^ rr8) << 3;                                  \
    const int ldsr = wid << 3;                                                \
    auto stageA = [&](int kt, int c, int h) {                                 \
        const size_t g0 = (size_t)(bm + (h << 7) + ldsr + rr8) * lda + (KBASE) + kt + cs; \
        gload16(A + g0,                      &sA[c][((h << 7) + ldsr) << 6]); \
        gload16(A + g0 + ((size_t)lda << 6), &sA[c][((h << 7) + 64 + ldsr) << 6]); \
    };                                                                        \
    auto stageB = [&](int kt, int c, int h) {                                 \
        const size_t g0 = (size_t)(bn + (h << 7) + ldsr + rr8) * ldb + (KBASE) + kt + cs; \
        gload16(B + g0,                      &sB[c][((h << 7) + ldsr) << 6]); \
        gload16(B + g0 + ((size_t)ldb << 6), &sB[c][((h << 7) + 64 + ldsr) << 6]); \
    };                                                                        \
    f32x4 acc[8][4] = {};                                                     \
    f16x8 a[4][2], b[2][2];                                                   \
    auto loadA = [&](int c, int qi) {                                         \
        _Pragma("unroll")                                                     \
        for (int i = 0; i < 4; ++i) {                                         \
            const int ra = wr * 128 + (qi * 4 + i) * 16 + (lane & 15);        \
            const int swz = (ra & 7) << 3;                                    \
            _Pragma("unroll")                                                 \
            for (int ks = 0; ks < 2; ++ks) {                                  \
                const int kk = ks * 32 + (lane >> 4) * 8;                     \
                a[i][ks] = *(const f16x8*)(&sA[c][(ra << 6) + (kk ^ swz)]);   \
            }                                                                 \
        }                                                                     \
    };                                                                        \
    auto loadB = [&](int c, int qj) {                                         \
        _Pragma("unroll")                                                     \
        for (int j = 0; j < 2; ++j) {                                         \
            const int rb = wc * 64 + (qj * 2 + j) * 16 + (lane & 15);         \
            const int swz = (rb & 7) << 3;                                    \
            _Pragma("unroll")                                                 \
            for (int ks = 0; ks < 2; ++ks) {                                  \
                const int kk = ks * 32 + (lane >> 4) * 8;                     \
                b[j][ks] = *(const f16x8*)(&sB[c][(rb << 6) + (kk ^ swz)]);   \
            }                                                                 \
        }                                                                     \
    };                                                                        \
    stageA(0, 0, 0); stageA(0, 0, 1); stageB(0, 0, 0); stageB(0, 0, 1);       \
    for (int g = 0; g < (NTILES); ++g) {                                      \
        const int c = g & 1, cn = c ^ 1;                                      \
        const int kn = (g + 1) << 6;                                          \
        const bool more = (g + 1) < (NTILES);                                 \
        /* ph1: issue next A, counted wait for tile g, quadrant (0,0) */      \
        if (more) {                                                           \
            stageA(kn, cn, 0); stageA(kn, cn, 1);                             \
            asm volatile("s_waitcnt vmcnt(4)" ::: "memory");                  \
        } else {                                                              \
            asm volatile("s_waitcnt vmcnt(0)" ::: "memory");                  \
        }                                                                     \
        BARRIER;                                                              \
        loadA(c, 0); loadB(c, 0);                                             \
        BARRIER; PHASE_MFMA(0, 0); BARRIER;                                   \
        /* ph2: issue next B, quadrant (0,1) */                               \
        if (more) { stageB(kn, cn, 0); stageB(kn, cn, 1); }                   \
        loadB(c, 1);                                                          \
        BARRIER; PHASE_MFMA(0, 1); BARRIER;                                   \
        /* ph3 */                                                             \
        loadA(c, 1); loadB(c, 0);                                             \
        BARRIER; PHASE_MFMA(1, 0); BARRIER;                                   \
        /* ph4 */                                                             \
        loadB(c, 1);                                                          \
        BARRIER; PHASE_MFMA(1, 1); BARRIER;                                   \
    }

// ===========================================================================
// Projection GEMM: C = A B^T, f16 in, f16 out, ldc-interleaved.
// ===========================================================================
template<bool F16OUT>
__global__ __launch_bounds__(512) void gemm_bt8(
    const f16* __restrict__ A, const f16* __restrict__ B, void* __restrict__ Cv,
    int K, int lda, int ldb, int ldc, float scale, int nbn)
{
    __shared__ f16 sA[2][256 * 64];
    __shared__ f16 sB[2][256 * 64];
    const int tid = threadIdx.x, lane = tid & 63, wid = tid >> 6;
    const int wr = wid >> 2, wc = wid & 3;
    const int cpx = gridDim.x >> 3;
    const int wg = (blockIdx.x & 7) * cpx + (blockIdx.x >> 3);
    const int bm = (wg / nbn) << 8, bn = (wg % nbn) << 8;

    BT8_BODY(0, K >> 6)

#pragma unroll
    for (int i = 0; i < 8; ++i)
#pragma unroll
        for (int j = 0; j < 4; ++j)
#pragma unroll
            for (int r = 0; r < 4; ++r) {
                const int row = bm + wr * 128 + i * 16 + ((lane >> 4) << 2) + r;
                const int col = bn + wc * 64 + j * 16 + (lane & 15);
                if constexpr (F16OUT)
                    ((f16*)Cv)[(size_t)row * ldc + col] = (f16)(acc[i][j][r] * scale);
                else
                    ((float*)Cv)[(size_t)row * ldc + col] = acc[i][j][r] * scale;
            }
}

// ===========================================================================
// QK: bt8 core, S written as plain f16 via LDS-transpose epilogue (verified
// r15: packed 16B stores, full-line coverage).
// ===========================================================================
__global__ __launch_bounds__(512) void gemm_qk(
    const f16* __restrict__ A, const f16* __restrict__ B,
    f16* __restrict__ S, int lda, int ldb)
{
    __shared__ f16 sA[2][256 * 64];
    __shared__ f16 sB[2][256 * 64];
    const int tid = threadIdx.x, lane = tid & 63, wid = tid >> 6;
    const int wr = wid >> 2, wc = wid & 3;
    const int cpx = gridDim.x >> 3;
    const int wg = (blockIdx.x & 7) * cpx + (blockIdx.x >> 3);
    const int bm = (wg >> 4) << 8, bn = (wg & 15) << 8;   // nbn = 16

    BT8_BODY(0, 16)

    // ---- acc -> LDS f16 (sA/sB dead; wr=0 half -> sA, wr=1 half -> sB) ----
    {
        f16* Tb = wr ? (f16*)sB : (f16*)sA;
        const int lg = lane >> 4;
#pragma unroll
        for (int i = 0; i < 8; ++i)
#pragma unroll
            for (int j = 0; j < 4; ++j)
#pragma unroll
                for (int r = 0; r < 4; ++r) {
                    const int rloc = i * 16 + lg * 4 + r;          // 0..127
                    const int col  = wc * 64 + j * 16 + (lane & 15);
                    Tb[rloc * 256 + (col ^ (((rloc >> 2) & 7) << 3))] = (f16)acc[i][j][r];
                }
    }
    BARRIER;
    // ---- LDS -> global: f16x8 per thread-iter, 512B contiguous per row ----
#pragma unroll
    for (int u = 0; u < 16; ++u) {
        const int gi = u * 512 + tid;
        const int row = gi >> 5;                 // 0..255
        const int c0 = (gi & 31) << 3;
        const f16* Tb = (row & 128) ? (const f16*)sB : (const f16*)sA;
        f16x8 v = *(const f16x8*)(Tb + (row & 127) * 256
                                  + (c0 ^ (((row >> 2) & 7) << 3)));
        *(f16x8*)(S + (size_t)(bm + row) * 4096 + bn + c0) = v;
    }
}

// ===========================================================================
// In-place row softmax on f16 S: P = exp(S - m) / (32 l), same location.
// ===========================================================================
__global__ __launch_bounds__(256) void softmax_f16(f16* S)
{
    const int lane = threadIdx.x & 63, wid = threadIdx.x >> 6;
    const int row = blockIdx.x * 4 + wid;
    f16* src = S + (size_t)row * 4096;
    f16x8 v[8];
#pragma unroll
    for (int u = 0; u < 8; ++u) v[u] = *(const f16x8*)(src + u * 512 + lane * 8);
    float m = -1e30f;
#pragma unroll
    for (int u = 0; u < 8; ++u)
#pragma unroll
        for (int e = 0; e < 8; ++e) m = fmaxf(m, (float)v[u][e]);
#pragma unroll
    for (int msk = 1; msk <= 32; msk <<= 1) m = fmaxf(m, __shfl_xor(m, msk));
    float ev[64];
    float s = 0.f;
#pragma unroll
    for (int u = 0; u < 8; ++u)
#pragma unroll
        for (int e = 0; e < 8; ++e) {
            const float x = __expf((float)v[u][e] - m);
            ev[u * 8 + e] = x; s += x;
        }
#pragma unroll
    for (int msk = 1; msk <= 32; msk <<= 1) s += __shfl_xor(s, msk);
    const float inv = 1.0f / (32.0f * s);
#pragma unroll
    for (int u = 0; u < 8; ++u) {
        f16x8 p;
#pragma unroll
        for (int e = 0; e < 8; ++e) p[e] = (f16)(ev[u * 8 + e] * inv);
        *(f16x8*)(src + u * 512 + lane * 8) = p;
    }
}

// ===========================================================================
// PV: bt8 core + split-K=4, plain stores. z=3 -> f32 direct to out;
// z=0..2 -> f16 partials [z][4096][1024].
// ===========================================================================
__global__ __launch_bounds__(512) void gemm_pv8(
    const f16* __restrict__ A, const f16* __restrict__ B, float* __restrict__ Cout,
    f16* __restrict__ Pp, int lda, int ldb)
{
    __shared__ f16 sA[2][256 * 64];
    __shared__ f16 sB[2][256 * 64];
    const int tid = threadIdx.x, lane = tid & 63, wid = tid >> 6;
    const int wr = wid >> 2, wc = wid & 3;
    const int cpx = gridDim.x >> 3;
    const int wg = (blockIdx.x & 7) * cpx + (blockIdx.x >> 3);
    const int bm = (wg >> 2) << 8, bn = (wg & 3) << 8;
    const int z = blockIdx.y;
    const int kbase = z << 10;

    BT8_BODY(kbase, 16)

#pragma unroll
    for (int i = 0; i < 8; ++i)
#pragma unroll
        for (int j = 0; j < 4; ++j)
#pragma unroll
            for (int r = 0; r < 4; ++r) {
                const int row = bm + wr * 128 + i * 16 + ((lane >> 4) << 2) + r;
                const int col = bn + wc * 64 + j * 16 + (lane & 15);
                const float v = acc[i][j][r];
                if (z == 3)
                    Cout[((size_t)row << 10) + col] = v;
                else
                    Pp[(size_t)z * 4194304 + ((size_t)row << 10) + col] = (f16)v;
            }
}

// ===========================================================================
// reduce_pv: out[r][c] = out[r][c](=p3) + p0 + p1 + p2 (flat partials).
// ===========================================================================
__global__ __launch_bounds__(256) void reduce_pv(
    float* __restrict__ Cout, const f16* __restrict__ Pp)
{
    const int i = blockIdx.x * 256 + threadIdx.x;
    const int r = i >> 7;
    const int c = (i & 127) << 3;
    const size_t base = ((size_t)r << 10) + c;
    const f16x8 p0 = *(const f16x8*)(Pp + base);
    const f16x8 p1 = *(const f16x8*)(Pp + base + 4194304);
    const f16x8 p2 = *(const f16x8*)(Pp + base + 8388608);
    float* o = Cout + base;
    float4 o0 = *(float4*)o, o1 = *(float4*)(o + 4);
    o0.x += (float)p0[0] + (float)p1[0] + (float)p2[0];
    o0.y += (float)p0[1] + (float)p1[1] + (float)p2[1];
    o0.z += (float)p0[2] + (float)p1[2] + (float)p2[2];
    o0.w += (float)p0[3] + (float)p1[3] + (float)p2[3];
    o1.x += (float)p0[4] + (float)p1[4] + (float)p2[4];
    o1.y += (float)p0[5] + (float)p1[5] + (float)p2[5];
    o1.z += (float)p0[6] + (float)p1[6] + (float)p2[6];
    o1.w += (float)p0[7] + (float)p1[7] + (float)p2[7];
    *(float4*)o = o0;
    *(float4*)(o + 4) = o1;
}

// ===========================================================================
// 128x128 BT-GEMM, F16IN + PIPE (verified) — used for vT.
// ===========================================================================
__global__ __launch_bounds__(256) void gemm_vt(
    const f16* __restrict__ A, const f16* __restrict__ B, f16* __restrict__ C,
    int K, int lda, int ldb, int ldc)
{
    __shared__ f16 sA[2][128 * 64];
    __shared__ f16 sB[2][128 * 64];
    const int tid = threadIdx.x, lane = tid & 63, wid = tid >> 6;
    const int wr = wid >> 1, wc = wid & 1;
    const int bm = blockIdx.x * 128, bn = blockIdx.y * 128;

    f32x4 acc[4][4] = {};

    auto stage16 = [&](int kt, int bsel) {
        const int rsub = lane >> 3;
        const int csw = ((lane & 7) ^ rsub) << 3;
#pragma unroll
        for (int i = 0; i < 4; ++i) {
            const int rb = (wid * 4 + i) * 8;
            gload16(A + (size_t)(bm + rb + rsub) * lda + kt + csw, &sA[bsel][rb * 64]);
            gload16(B + (size_t)(bn + rb + rsub) * ldb + kt + csw, &sB[bsel][rb * 64]);
        }
    };

    auto compute = [&](int bsel) {
#pragma unroll
        for (int ks = 0; ks < 2; ++ks) {
            const int kk = ks * 32 + (lane >> 4) * 8;
            f16x8 a[4], b[4];
#pragma unroll
            for (int i = 0; i < 4; ++i) {
                const int ra = wr * 64 + i * 16 + (lane & 15);
                a[i] = *(const f16x8*)(&sA[bsel][(ra << 6) + (kk ^ ((ra & 7) << 3))]);
                const int rb2 = wc * 64 + i * 16 + (lane & 15);
                b[i] = *(const f16x8*)(&sB[bsel][(rb2 << 6) + (kk ^ ((rb2 & 7) << 3))]);
            }
#pragma unroll
            for (int i = 0; i < 4; ++i)
#pragma unroll
                for (int j = 0; j < 4; ++j)
                    acc[i][j] = __builtin_amdgcn_mfma_f32_16x16x32_f16(a[i], b[j], acc[i][j], 0, 0, 0);
        }
    };

    stage16(0, 0);
    asm volatile("s_waitcnt vmcnt(0)" ::: "memory");
    __syncthreads();
    const int NT2 = K >> 6;
    for (int t = 0; t < NT2; ++t) {
        if (t + 1 < NT2) stage16((t + 1) << 6, (t + 1) & 1);
        compute(t & 1);
        asm volatile("s_waitcnt vmcnt(0)" ::: "memory");
        __builtin_amdgcn_s_barrier();
    }
#pragma unroll
    for (int i = 0; i < 4; ++i)
#pragma unroll
        for (int j = 0; j < 4; ++j)
#pragma unroll
            for (int r = 0; r < 4; ++r) {
                const int row = bm + wr * 64 + i * 16 + (lane >> 4) * 4 + r;
                const int col = bn + wc * 64 + j * 16 + (lane & 15);
                C[(size_t)row * ldc + col] = (f16)acc[i][j][r];
            }
}

// ---------------------------------------------------------------------------
// Merged upfront convert: x (2097152 x8), Wq (131072 x8), Wk (131072 x8).
// ---------------------------------------------------------------------------
__global__ __launch_bounds__(256) void cvt3(
    const float* __restrict__ x, const float* __restrict__ wq, const float* __restrict__ wk,
    f16* __restrict__ dx, f16* __restrict__ dwq, f16* __restrict__ dwk)
{
    const int i = blockIdx.x * 256 + threadIdx.x;
    const float* s; f16* d; int off;
    if (i < 2097152)      { s = x;  d = dx;  off = i; }
    else if (i < 2228224) { s = wq; d = dwq; off = i - 2097152; }
    else                  { s = wk; d = dwk; off = i - 2228224; }
    const float4 a = ((const float4*)s)[off * 2];
    const float4 b = ((const float4*)s)[off * 2 + 1];
    f16x8 o = { (f16)a.x, (f16)a.y, (f16)a.z, (f16)a.w,
                (f16)b.x, (f16)b.y, (f16)b.z, (f16)b.w };
    ((f16x8*)d)[off] = o;
}

// Merged per-batch convert: x_b (524288 x8) + Wv (131072 x8).
__global__ __launch_bounds__(256) void cvt_batch(
    const float* __restrict__ xb, const float* __restrict__ wv,
    f16* __restrict__ dxb, f16* __restrict__ dwv)
{
    const int i = blockIdx.x * 256 + threadIdx.x;
    const float* s; f16* d; int off;
    if (i < 524288) { s = xb; d = dxb; off = i; }
    else            { s = wv; d = dwv; off = i - 524288; }
    const float4 a = ((const float4*)s)[off * 2];
    const float4 b = ((const float4*)s)[off * 2 + 1];
    f16x8 o = { (f16)a.x, (f16)a.y, (f16)a.z, (f16)a.w,
                (f16)b.x, (f16)b.y, (f16)b.z, (f16)b.w };
    ((f16x8*)d)[off] = o;
}

// ---------------------------------------------------------------------------
// Pipeline: cvt3 -> proj(bt8 x2) -> per batch { QK(f16 S, LDS-transpose) ->
// softmax_f16(in place) -> cvt_batch -> vT(PIPE) -> PV(split-K=4) -> reduce }.
// ws: S/P f16 [4096][4096] @0 (32MB); partials [3][4096][1024] @32MB (24MB);
// vT [1024][4096] @56MB (8MB). Pre-loop: xh@0, wqh/wkh@32MB (dead after proj).
// ---------------------------------------------------------------------------
extern "C" void kernel_launch(void* const* d_in, const int* in_sizes, int n_in,
                              void* d_out, int out_size, void* d_ws, size_t ws_size,
                              hipStream_t stream) {
    const float* x  = (const float*)d_in[0];   // [4,4096,1024]
    const float* Wq = (const float*)d_in[1];   // [1024,1024]
    const float* Wk = (const float*)d_in[2];
    const float* Wv = (const float*)d_in[3];
    float* out = (float*)d_out;                // [4,4096,1024] fp32

    f16*   qk  = (f16*)d_out;                  // q even 1KB-slots, k odd
    f16*   xh  = (f16*)d_ws;                   // 32 MB (transient)
    f16*   wqh = (f16*)((char*)d_ws + (32LL << 20));   // 2 MB (transient)
    f16*   wkh = wqh + 1024LL * 1024;                  // 2 MB (transient)

    f16*   S   = (f16*)d_ws;                                  // 32 MB S/P
    f16*   Pp  = (f16*)((char*)d_ws + (32LL << 20));          // 24 MB partials
    f16*   vTw = (f16*)((char*)d_ws + (56LL << 20));          // 8 MB vT

    cvt3<<<9216, 256, 0, stream>>>(x, Wq, Wk, xh, wqh, wkh);

    gemm_bt8<true><<<256, 512, 0, stream>>>(xh, wqh, qk,        1024, 1024, 1024, 2048, 1.f, 4);
    gemm_bt8<true><<<256, 512, 0, stream>>>(xh, wkh, qk + 1024, 1024, 1024, 1024, 2048, 1.f, 4);

    for (int b = 0; b < 4; ++b) {
        const size_t tb = (size_t)b * 4096;
        f16* xhb = (f16*)(out + tb * 1024);        // dead q_b/k_b region
        f16* wvh = xhb + 4096LL * 1024;            // +8 MB
        // S = q_b k_b^T  (f16, packed stores via LDS transpose)
        gemm_qk<<<256, 512, 0, stream>>>(
            qk + tb * 2048, qk + tb * 2048 + 1024, S, 2048, 2048);
        // P = exp(S - m) / (32 l), in place
        softmax_f16<<<1024, 256, 0, stream>>>(S);
        // cvt x_b + Wv into dead out_b region (one launch)
        cvt_batch<<<2560, 256, 0, stream>>>(x + tb * 1024, Wv, xhb, wvh);
        // vT_b = Wv_h x_b^T -> ws[56:64), ldc 4096
        gemm_vt<<<dim3(8, 32), 256, 0, stream>>>(wvh, xhb, vTw, 1024, 1024, 1024, 4096);
        // att_b = P vT^T: split-K=4, then reduce
        gemm_pv8<<<dim3(64, 4), 512, 0, stream>>>(S, vTw, out + tb * 1024, Pp, 4096, 4096);
        reduce_pv<<<2048, 256, 0, stream>>>(out + tb * 1024, Pp);
    }
}

// Round 17
// 582.183 us; speedup vs baseline: 1.1568x; 1.1568x over previous
//
#include <hip/hip_runtime.h>
#include <hip/hip_bf16.h>

typedef _Float16 f16;
typedef _Float16 f16x4 __attribute__((ext_vector_type(4)));
typedef _Float16 f16x8 __attribute__((ext_vector_type(8)));
typedef float f32x4 __attribute__((ext_vector_type(4)));

__device__ __forceinline__ void gload16(const void* g, void* l) {
    __builtin_amdgcn_global_load_lds(
        (const __attribute__((address_space(1))) void*)g,
        (__attribute__((address_space(3))) void*)l, 16, 0, 0);
}

#define FENCE asm volatile("" ::: "memory")
#define BARRIER do { FENCE; __builtin_amdgcn_s_barrier(); FENCE; } while (0)

// ===========================================================================
// 256x256 BT-GEMM core, r17: ONE barrier per K-tile.
// Tile g: stage(g+1 -> buf cn) FIRST (max drain cover); then per ks-half:
// 12 ds_reads (a[8],b[4]) + 32 MFMA (lgkm-gated, no barrier needed: no
// cross-wave hazard inside a tile); then vmcnt(0) (drains g+1's loads with
// ~full-tile cover >> HBM latency) + barrier.
// Safety: stage(cn) after barrier g-1 => cn's ds_reads (tile g-1) retired.
// reads(c): staged at g-1 start, drained at g-1's vmcnt+barrier.
// B fragments read once per tile (was twice in the 8-phase version).
// ===========================================================================
#define BT8_BODY(KBASE, NTILES)                                               \
    const int rr8 = lane >> 3;                                                \
    const int cs  = ((lane & 7) ^ rr8) << 3;                                  \
    const int ldsr = wid << 3;                                                \
    auto stageA = [&](int kt, int c, int h) {                                 \
        const size_t g0 = (size_t)(bm + (h << 7) + ldsr + rr8) * lda + (KBASE) + kt + cs; \
        gload16(A + g0,                      &sA[c][((h << 7) + ldsr) << 6]); \
        gload16(A + g0 + ((size_t)lda << 6), &sA[c][((h << 7) + 64 + ldsr) << 6]); \
    };                                                                        \
    auto stageB = [&](int kt, int c, int h) {                                 \
        const size_t g0 = (size_t)(bn + (h << 7) + ldsr + rr8) * ldb + (KBASE) + kt + cs; \
        gload16(B + g0,                      &sB[c][((h << 7) + ldsr) << 6]); \
        gload16(B + g0 + ((size_t)ldb << 6), &sB[c][((h << 7) + 64 + ldsr) << 6]); \
    };                                                                        \
    f32x4 acc[8][4] = {};                                                     \
    stageA(0, 0, 0); stageA(0, 0, 1); stageB(0, 0, 0); stageB(0, 0, 1);       \
    asm volatile("s_waitcnt vmcnt(0)" ::: "memory");                          \
    BARRIER;                                                                  \
    for (int g = 0; g < (NTILES); ++g) {                                      \
        const int c = g & 1, cn = c ^ 1;                                      \
        const int kn = (g + 1) << 6;                                          \
        const bool more = (g + 1) < (NTILES);                                 \
        if (more) { stageA(kn, cn, 0); stageA(kn, cn, 1);                     \
                    stageB(kn, cn, 0); stageB(kn, cn, 1); }                   \
        _Pragma("unroll")                                                     \
        for (int ks = 0; ks < 2; ++ks) {                                      \
            f16x8 a[8], b[4];                                                 \
            const int kk = ks * 32 + ((lane >> 4) << 3);                      \
            _Pragma("unroll")                                                 \
            for (int i = 0; i < 8; ++i) {                                     \
                const int ra = wr * 128 + i * 16 + (lane & 15);               \
                a[i] = *(const f16x8*)(&sA[c][(ra << 6) + (kk ^ ((ra & 7) << 3))]); \
            }                                                                 \
            _Pragma("unroll")                                                 \
            for (int j = 0; j < 4; ++j) {                                     \
                const int rb = wc * 64 + j * 16 + (lane & 15);                \
                b[j] = *(const f16x8*)(&sB[c][(rb << 6) + (kk ^ ((rb & 7) << 3))]); \
            }                                                                 \
            __builtin_amdgcn_s_setprio(1);                                    \
            _Pragma("unroll")                                                 \
            for (int i = 0; i < 8; ++i)                                       \
                _Pragma("unroll")                                             \
                for (int j = 0; j < 4; ++j)                                   \
                    acc[i][j] = __builtin_amdgcn_mfma_f32_16x16x32_f16(       \
                        a[i], b[j], acc[i][j], 0, 0, 0);                      \
            __builtin_amdgcn_s_setprio(0);                                    \
        }                                                                     \
        asm volatile("s_waitcnt vmcnt(0)" ::: "memory");                      \
        BARRIER;                                                              \
    }

// ===========================================================================
// Projection GEMM: C = A B^T, f16 in, f16 out, ldc-interleaved.
// ===========================================================================
template<bool F16OUT>
__global__ __launch_bounds__(512) void gemm_bt8(
    const f16* __restrict__ A, const f16* __restrict__ B, void* __restrict__ Cv,
    int K, int lda, int ldb, int ldc, float scale, int nbn)
{
    __shared__ f16 sA[2][256 * 64];
    __shared__ f16 sB[2][256 * 64];
    const int tid = threadIdx.x, lane = tid & 63, wid = tid >> 6;
    const int wr = wid >> 2, wc = wid & 3;
    const int cpx = gridDim.x >> 3;
    const int wg = (blockIdx.x & 7) * cpx + (blockIdx.x >> 3);
    const int bm = (wg / nbn) << 8, bn = (wg % nbn) << 8;

    BT8_BODY(0, K >> 6)

#pragma unroll
    for (int i = 0; i < 8; ++i)
#pragma unroll
        for (int j = 0; j < 4; ++j)
#pragma unroll
            for (int r = 0; r < 4; ++r) {
                const int row = bm + wr * 128 + i * 16 + ((lane >> 4) << 2) + r;
                const int col = bn + wc * 64 + j * 16 + (lane & 15);
                if constexpr (F16OUT)
                    ((f16*)Cv)[(size_t)row * ldc + col] = (f16)(acc[i][j][r] * scale);
                else
                    ((float*)Cv)[(size_t)row * ldc + col] = acc[i][j][r] * scale;
            }
}

// ===========================================================================
// QK: bt8 core, S written as plain f16 via LDS-transpose epilogue (verified
// r15: packed 16B stores, full-line coverage).
// ===========================================================================
__global__ __launch_bounds__(512) void gemm_qk(
    const f16* __restrict__ A, const f16* __restrict__ B,
    f16* __restrict__ S, int lda, int ldb)
{
    __shared__ f16 sA[2][256 * 64];
    __shared__ f16 sB[2][256 * 64];
    const int tid = threadIdx.x, lane = tid & 63, wid = tid >> 6;
    const int wr = wid >> 2, wc = wid & 3;
    const int cpx = gridDim.x >> 3;
    const int wg = (blockIdx.x & 7) * cpx + (blockIdx.x >> 3);
    const int bm = (wg >> 4) << 8, bn = (wg & 15) << 8;   // nbn = 16

    BT8_BODY(0, 16)

    // ---- acc -> LDS f16 (sA/sB dead; wr=0 half -> sA, wr=1 half -> sB) ----
    {
        f16* Tb = wr ? (f16*)sB : (f16*)sA;
        const int lg = lane >> 4;
#pragma unroll
        for (int i = 0; i < 8; ++i)
#pragma unroll
            for (int j = 0; j < 4; ++j)
#pragma unroll
                for (int r = 0; r < 4; ++r) {
                    const int rloc = i * 16 + lg * 4 + r;          // 0..127
                    const int col  = wc * 64 + j * 16 + (lane & 15);
                    Tb[rloc * 256 + (col ^ (((rloc >> 2) & 7) << 3))] = (f16)acc[i][j][r];
                }
    }
    BARRIER;
    // ---- LDS -> global: f16x8 per thread-iter, 512B contiguous per row ----
#pragma unroll
    for (int u = 0; u < 16; ++u) {
        const int gi = u * 512 + tid;
        const int row = gi >> 5;                 // 0..255
        const int c0 = (gi & 31) << 3;
        const f16* Tb = (row & 128) ? (const f16*)sB : (const f16*)sA;
        f16x8 v = *(const f16x8*)(Tb + (row & 127) * 256
                                  + (c0 ^ (((row >> 2) & 7) << 3)));
        *(f16x8*)(S + (size_t)(bm + row) * 4096 + bn + c0) = v;
    }
}

// ===========================================================================
// In-place row softmax on f16 S: P = exp(S - m) / (32 l), same location.
// ===========================================================================
__global__ __launch_bounds__(256) void softmax_f16(f16* S)
{
    const int lane = threadIdx.x & 63, wid = threadIdx.x >> 6;
    const int row = blockIdx.x * 4 + wid;
    f16* src = S + (size_t)row * 4096;
    f16x8 v[8];
#pragma unroll
    for (int u = 0; u < 8; ++u) v[u] = *(const f16x8*)(src + u * 512 + lane * 8);
    float m = -1e30f;
#pragma unroll
    for (int u = 0; u < 8; ++u)
#pragma unroll
        for (int e = 0; e < 8; ++e) m = fmaxf(m, (float)v[u][e]);
#pragma unroll
    for (int msk = 1; msk <= 32; msk <<= 1) m = fmaxf(m, __shfl_xor(m, msk));
    float ev[64];
    float s = 0.f;
#pragma unroll
    for (int u = 0; u < 8; ++u)
#pragma unroll
        for (int e = 0; e < 8; ++e) {
            const float x = __expf((float)v[u][e] - m);
            ev[u * 8 + e] = x; s += x;
        }
#pragma unroll
    for (int msk = 1; msk <= 32; msk <<= 1) s += __shfl_xor(s, msk);
    const float inv = 1.0f / (32.0f * s);
#pragma unroll
    for (int u = 0; u < 8; ++u) {
        f16x8 p;
#pragma unroll
        for (int e = 0; e < 8; ++e) p[e] = (f16)(ev[u * 8 + e] * inv);
        *(f16x8*)(src + u * 512 + lane * 8) = p;
    }
}

// ===========================================================================
// PV: bt8 core + split-K=4, plain stores. z=3 -> f32 direct to out;
// z=0..2 -> f16 partials [z][4096][1024].
// ===========================================================================
__global__ __launch_bounds__(512) void gemm_pv8(
    const f16* __restrict__ A, const f16* __restrict__ B, float* __restrict__ Cout,
    f16* __restrict__ Pp, int lda, int ldb)
{
    __shared__ f16 sA[2][256 * 64];
    __shared__ f16 sB[2][256 * 64];
    const int tid = threadIdx.x, lane = tid & 63, wid = tid >> 6;
    const int wr = wid >> 2, wc = wid & 3;
    const int cpx = gridDim.x >> 3;
    const int wg = (blockIdx.x & 7) * cpx + (blockIdx.x >> 3);
    const int bm = (wg >> 2) << 8, bn = (wg & 3) << 8;
    const int z = blockIdx.y;
    const int kbase = z << 10;

    BT8_BODY(kbase, 16)

#pragma unroll
    for (int i = 0; i < 8; ++i)
#pragma unroll
        for (int j = 0; j < 4; ++j)
#pragma unroll
            for (int r = 0; r < 4; ++r) {
                const int row = bm + wr * 128 + i * 16 + ((lane >> 4) << 2) + r;
                const int col = bn + wc * 64 + j * 16 + (lane & 15);
                const float v = acc[i][j][r];
                if (z == 3)
                    Cout[((size_t)row << 10) + col] = v;
                else
                    Pp[(size_t)z * 4194304 + ((size_t)row << 10) + col] = (f16)v;
            }
}

// ===========================================================================
// reduce_pv: out[r][c] = out[r][c](=p3) + p0 + p1 + p2 (flat partials).
// ===========================================================================
__global__ __launch_bounds__(256) void reduce_pv(
    float* __restrict__ Cout, const f16* __restrict__ Pp)
{
    const int i = blockIdx.x * 256 + threadIdx.x;
    const int r = i >> 7;
    const int c = (i & 127) << 3;
    const size_t base = ((size_t)r << 10) + c;
    const f16x8 p0 = *(const f16x8*)(Pp + base);
    const f16x8 p1 = *(const f16x8*)(Pp + base + 4194304);
    const f16x8 p2 = *(const f16x8*)(Pp + base + 8388608);
    float* o = Cout + base;
    float4 o0 = *(float4*)o, o1 = *(float4*)(o + 4);
    o0.x += (float)p0[0] + (float)p1[0] + (float)p2[0];
    o0.y += (float)p0[1] + (float)p1[1] + (float)p2[1];
    o0.z += (float)p0[2] + (float)p1[2] + (float)p2[2];
    o0.w += (float)p0[3] + (float)p1[3] + (float)p2[3];
    o1.x += (float)p0[4] + (float)p1[4] + (float)p2[4];
    o1.y += (float)p0[5] + (float)p1[5] + (float)p2[5];
    o1.z += (float)p0[6] + (float)p1[6] + (float)p2[6];
    o1.w += (float)p0[7] + (float)p1[7] + (float)p2[7];
    *(float4*)o = o0;
    *(float4*)(o + 4) = o1;
}

// ===========================================================================
// 128x128 BT-GEMM, F16IN + PIPE (verified) — used for vT.
// ===========================================================================
__global__ __launch_bounds__(256) void gemm_vt(
    const f16* __restrict__ A, const f16* __restrict__ B, f16* __restrict__ C,
    int K, int lda, int ldb, int ldc)
{
    __shared__ f16 sA[2][128 * 64];
    __shared__ f16 sB[2][128 * 64];
    const int tid = threadIdx.x, lane = tid & 63, wid = tid >> 6;
    const int wr = wid >> 1, wc = wid & 1;
    const int bm = blockIdx.x * 128, bn = blockIdx.y * 128;

    f32x4 acc[4][4] = {};

    auto stage16 = [&](int kt, int bsel) {
        const int rsub = lane >> 3;
        const int csw = ((lane & 7) ^ rsub) << 3;
#pragma unroll
        for (int i = 0; i < 4; ++i) {
            const int rb = (wid * 4 + i) * 8;
            gload16(A + (size_t)(bm + rb + rsub) * lda + kt + csw, &sA[bsel][rb * 64]);
            gload16(B + (size_t)(bn + rb + rsub) * ldb + kt + csw, &sB[bsel][rb * 64]);
        }
    };

    auto compute = [&](int bsel) {
#pragma unroll
        for (int ks = 0; ks < 2; ++ks) {
            const int kk = ks * 32 + (lane >> 4) * 8;
            f16x8 a[4], b[4];
#pragma unroll
            for (int i = 0; i < 4; ++i) {
                const int ra = wr * 64 + i * 16 + (lane & 15);
                a[i] = *(const f16x8*)(&sA[bsel][(ra << 6) + (kk ^ ((ra & 7) << 3))]);
                const int rb2 = wc * 64 + i * 16 + (lane & 15);
                b[i] = *(const f16x8*)(&sB[bsel][(rb2 << 6) + (kk ^ ((rb2 & 7) << 3))]);
            }
#pragma unroll
            for (int i = 0; i < 4; ++i)
#pragma unroll
                for (int j = 0; j < 4; ++j)
                    acc[i][j] = __builtin_amdgcn_mfma_f32_16x16x32_f16(a[i], b[j], acc[i][j], 0, 0, 0);
        }
    };

    stage16(0, 0);
    asm volatile("s_waitcnt vmcnt(0)" ::: "memory");
    __syncthreads();
    const int NT2 = K >> 6;
    for (int t = 0; t < NT2; ++t) {
        if (t + 1 < NT2) stage16((t + 1) << 6, (t + 1) & 1);
        compute(t & 1);
        asm volatile("s_waitcnt vmcnt(0)" ::: "memory");
        __builtin_amdgcn_s_barrier();
    }
#pragma unroll
    for (int i = 0; i < 4; ++i)
#pragma unroll
        for (int j = 0; j < 4; ++j)
#pragma unroll
            for (int r = 0; r < 4; ++r) {
                const int row = bm + wr * 64 + i * 16 + (lane >> 4) * 4 + r;
                const int col = bn + wc * 64 + j * 16 + (lane & 15);
                C[(size_t)row * ldc + col] = (f16)acc[i][j][r];
            }
}

// ---------------------------------------------------------------------------
// Merged upfront convert: x (2097152 x8), Wq (131072 x8), Wk (131072 x8).
// ---------------------------------------------------------------------------
__global__ __launch_bounds__(256) void cvt3(
    const float* __restrict__ x, const float* __restrict__ wq, const float* __restrict__ wk,
    f16* __restrict__ dx, f16* __restrict__ dwq, f16* __restrict__ dwk)
{
    const int i = blockIdx.x * 256 + threadIdx.x;
    const float* s; f16* d; int off;
    if (i < 2097152)      { s = x;  d = dx;  off = i; }
    else if (i < 2228224) { s = wq; d = dwq; off = i - 2097152; }
    else                  { s = wk; d = dwk; off = i - 2228224; }
    const float4 a = ((const float4*)s)[off * 2];
    const float4 b = ((const float4*)s)[off * 2 + 1];
    f16x8 o = { (f16)a.x, (f16)a.y, (f16)a.z, (f16)a.w,
                (f16)b.x, (f16)b.y, (f16)b.z, (f16)b.w };
    ((f16x8*)d)[off] = o;
}

// Merged per-batch convert: x_b (524288 x8) + Wv (131072 x8).
__global__ __launch_bounds__(256) void cvt_batch(
    const float* __restrict__ xb, const float* __restrict__ wv,
    f16* __restrict__ dxb, f16* __restrict__ dwv)
{
    const int i = blockIdx.x * 256 + threadIdx.x;
    const float* s; f16* d; int off;
    if (i < 524288) { s = xb; d = dxb; off = i; }
    else            { s = wv; d = dwv; off = i - 524288; }
    const float4 a = ((const float4*)s)[off * 2];
    const float4 b = ((const float4*)s)[off * 2 + 1];
    f16x8 o = { (f16)a.x, (f16)a.y, (f16)a.z, (f16)a.w,
                (f16)b.x, (f16)b.y, (f16)b.z, (f16)b.w };
    ((f16x8*)d)[off] = o;
}

// ---------------------------------------------------------------------------
// Pipeline: cvt3 -> proj(bt8 x2) -> per batch { QK(f16 S, LDS-transpose) ->
// softmax_f16(in place) -> cvt_batch -> vT(PIPE) -> PV(split-K=4) -> reduce }.
// ws: S/P f16 [4096][4096] @0 (32MB); partials [3][4096][1024] @32MB (24MB);
// vT [1024][4096] @56MB (8MB). Pre-loop: xh@0, wqh/wkh@32MB (dead after proj).
// ---------------------------------------------------------------------------
extern "C" void kernel_launch(void* const* d_in, const int* in_sizes, int n_in,
                              void* d_out, int out_size, void* d_ws, size_t ws_size,
                              hipStream_t stream) {
    const float* x  = (const float*)d_in[0];   // [4,4096,1024]
    const float* Wq = (const float*)d_in[1];   // [1024,1024]
    const float* Wk = (const float*)d_in[2];
    const float* Wv = (const float*)d_in[3];
    float* out = (float*)d_out;                // [4,4096,1024] fp32

    f16*   qk  = (f16*)d_out;                  // q even 1KB-slots, k odd
    f16*   xh  = (f16*)d_ws;                   // 32 MB (transient)
    f16*   wqh = (f16*)((char*)d_ws + (32LL << 20));   // 2 MB (transient)
    f16*   wkh = wqh + 1024LL * 1024;                  // 2 MB (transient)

    f16*   S   = (f16*)d_ws;                                  // 32 MB S/P
    f16*   Pp  = (f16*)((char*)d_ws + (32LL << 20));          // 24 MB partials
    f16*   vTw = (f16*)((char*)d_ws + (56LL << 20));          // 8 MB vT

    cvt3<<<9216, 256, 0, stream>>>(x, Wq, Wk, xh, wqh, wkh);

    gemm_bt8<true><<<256, 512, 0, stream>>>(xh, wqh, qk,        1024, 1024, 1024, 2048, 1.f, 4);
    gemm_bt8<true><<<256, 512, 0, stream>>>(xh, wkh, qk + 1024, 1024, 1024, 1024, 2048, 1.f, 4);

    for (int b = 0; b < 4; ++b) {
        const size_t tb = (size_t)b * 4096;
        f16* xhb = (f16*)(out + tb * 1024);        // dead q_b/k_b region
        f16* wvh = xhb + 4096LL * 1024;            // +8 MB
        // S = q_b k_b^T  (f16, packed stores via LDS transpose)
        gemm_qk<<<256, 512, 0, stream>>>(
            qk + tb * 2048, qk + tb * 2048 + 1024, S, 2048, 2048);
        // P = exp(S - m) / (32 l), in place
        softmax_f16<<<1024, 256, 0, stream>>>(S);
        // cvt x_b + Wv into dead out_b region (one launch)
        cvt_batch<<<2560, 256, 0, stream>>>(x + tb * 1024, Wv, xhb, wvh);
        // vT_b = Wv_h x_b^T -> ws[56:64), ldc 4096
        gemm_vt<<<dim3(8, 32), 256, 0, stream>>>(wvh, xhb, vTw, 1024, 1024, 1024, 4096);
        // att_b = P vT^T: split-K=4, then reduce
        gemm_pv8<<<dim3(64, 4), 512, 0, stream>>>(S, vTw, out + tb * 1024, Pp, 4096, 4096);
        reduce_pv<<<2048, 256, 0, stream>>>(out + tb * 1024, Pp);
    }
}

// Round 18
// 569.083 us; speedup vs baseline: 1.1834x; 1.0230x over previous
//
#include <hip/hip_runtime.h>
#include <hip/hip_bf16.h>

typedef _Float16 f16;
typedef _Float16 f16x4 __attribute__((ext_vector_type(4)));
typedef _Float16 f16x8 __attribute__((ext_vector_type(8)));
typedef float f32x4 __attribute__((ext_vector_type(4)));

__device__ __forceinline__ void gload16(const void* g, void* l) {
    __builtin_amdgcn_global_load_lds(
        (const __attribute__((address_space(1))) void*)g,
        (__attribute__((address_space(3))) void*)l, 16, 0, 0);
}

#define FENCE asm volatile("" ::: "memory")
#define BARRIER do { FENCE; __builtin_amdgcn_s_barrier(); FENCE; } while (0)

// ===========================================================================
// 256x256 BT-GEMM core r18: m201-faithful counted-vmcnt schedule.
// 2 K-tiles/iter (even tile -> buf0, odd -> buf1), 8 phases/iter, one
// half-tile staged per slot at its buffer-free point:
//   ph1: A1(O),B0(O)  ph2: B1(O)  ph4: A0(E')  ph5: A1(E'),B0(E')
//   ph6: B1(E')       ph8: A0(O')
// Waits: vmcnt(6) at ph1 & ph5 only (queue=14, oldest 8 = tile about to be
// read; 3-5 phases of cover per half). Last iter: vmcnt(0) at ph5.
// Reads: read-once (24 ds_read_b128/tile): ph1 aq0+b01, ph2 b23, ph3 aq1.
// ===========================================================================
#define PHASE_MFMA(QI, QJ)                                                    \
    __builtin_amdgcn_s_setprio(1);                                            \
    _Pragma("unroll")                                                         \
    for (int ks = 0; ks < 2; ++ks)                                            \
      _Pragma("unroll")                                                       \
      for (int i = 0; i < 4; ++i)                                             \
        _Pragma("unroll")                                                     \
        for (int j = 0; j < 2; ++j)                                           \
          acc[(QI)*4 + i][(QJ)*2 + j] = __builtin_amdgcn_mfma_f32_16x16x32_f16( \
              a[i][ks], b[(QJ)*2 + j][ks], acc[(QI)*4 + i][(QJ)*2 + j], 0, 0, 0); \
    __builtin_amdgcn_s_setprio(0);

#define BT8_BODY(KBASE, NTILES)                                               \
    const int rr8 = lane >> 3;                                                \
    const int cs  = ((lane & 7) ^ rr8) << 3;                                  \
    const int ldsr = wid << 3;                                                \
    auto stageA = [&](int kt, int c, int h) {                                 \
        const size_t g0 = (size_t)(bm + (h << 7) + ldsr + rr8) * lda + (KBASE) + kt + cs; \
        gload16(A + g0,                      &sA[c][((h << 7) + ldsr) << 6]); \
        gload16(A + g0 + ((size_t)lda << 6), &sA[c][((h << 7) + 64 + ldsr) << 6]); \
    };                                                                        \
    auto stageB = [&](int kt, int c, int h) {                                 \
        const size_t g0 = (size_t)(bn + (h << 7) + ldsr + rr8) * ldb + (KBASE) + kt + cs; \
        gload16(B + g0,                      &sB[c][((h << 7) + ldsr) << 6]); \
        gload16(B + g0 + ((size_t)ldb << 6), &sB[c][((h << 7) + 64 + ldsr) << 6]); \
    };                                                                        \
    f32x4 acc[8][4] = {};                                                     \
    f16x8 a[4][2], b[4][2];                                                   \
    auto loadA = [&](int c, int qi) {                                         \
        _Pragma("unroll")                                                     \
        for (int i = 0; i < 4; ++i) {                                         \
            const int ra = wr * 128 + (qi * 4 + i) * 16 + (lane & 15);        \
            const int swz = (ra & 7) << 3;                                    \
            _Pragma("unroll")                                                 \
            for (int ks = 0; ks < 2; ++ks) {                                  \
                const int kk = ks * 32 + ((lane >> 4) << 3);                  \
                a[i][ks] = *(const f16x8*)(&sA[c][(ra << 6) + (kk ^ swz)]);   \
            }                                                                 \
        }                                                                     \
    };                                                                        \
    auto loadB = [&](int c, int qj) {                                         \
        _Pragma("unroll")                                                     \
        for (int j = 0; j < 2; ++j) {                                         \
            const int rb = wc * 64 + (qj * 2 + j) * 16 + (lane & 15);         \
            const int swz = (rb & 7) << 3;                                    \
            _Pragma("unroll")                                                 \
            for (int ks = 0; ks < 2; ++ks) {                                  \
                const int kk = ks * 32 + ((lane >> 4) << 3);                  \
                b[qj * 2 + j][ks] = *(const f16x8*)(&sB[c][(rb << 6) + (kk ^ swz)]); \
            }                                                                 \
        }                                                                     \
    };                                                                        \
    /* prologue: T0 all 4 halves + A0(T1)  (queue: 10 loads/thread) */        \
    stageA(0, 0, 0); stageA(0, 0, 1); stageB(0, 0, 0); stageB(0, 0, 1);       \
    stageA(64, 1, 0);                                                         \
    for (int g2 = 0; g2 < (NTILES); g2 += 2) {                                \
        const bool more = (g2 + 2) < (NTILES);                                \
        const int kO  = (g2 + 1) << 6;                                        \
        const int kE2 = (g2 + 2) << 6;                                        \
        const int kO2 = (g2 + 3) << 6;                                        \
        /* ph1: stage A1(O),B0(O); counted wait for tile E; read aq0,b01 */   \
        stageA(kO, 1, 1); stageB(kO, 1, 0);                                   \
        asm volatile("s_waitcnt vmcnt(6)" ::: "memory");                      \
        BARRIER;                                                              \
        loadA(0, 0); loadB(0, 0);                                             \
        PHASE_MFMA(0, 0);                                                     \
        BARRIER;                                                              \
        /* ph2: stage B1(O); read b23(E) */                                   \
        stageB(kO, 1, 1);                                                     \
        loadB(0, 1);                                                          \
        PHASE_MFMA(0, 1);                                                     \
        BARRIER;                                                              \
        /* ph3: read aq1(E) */                                                \
        loadA(0, 1);                                                          \
        PHASE_MFMA(1, 0);                                                     \
        BARRIER;                                                              \
        /* ph4: stage A0(E') */                                               \
        if (more) stageA(kE2, 0, 0);                                          \
        PHASE_MFMA(1, 1);                                                     \
        BARRIER;                                                              \
        /* ph5: stage A1(E'),B0(E'); counted wait for tile O; read aq0,b01 */ \
        if (more) {                                                           \
            stageA(kE2, 0, 1); stageB(kE2, 0, 0);                             \
            asm volatile("s_waitcnt vmcnt(6)" ::: "memory");                  \
        } else {                                                              \
            asm volatile("s_waitcnt vmcnt(0)" ::: "memory");                  \
        }                                                                     \
        BARRIER;                                                              \
        loadA(1, 0); loadB(1, 0);                                             \
        PHASE_MFMA(0, 0);                                                     \
        BARRIER;                                                              \
        /* ph6: stage B1(E'); read b23(O) */                                  \
        if (more) stageB(kE2, 0, 1);                                          \
        loadB(1, 1);                                                          \
        PHASE_MFMA(0, 1);                                                     \
        BARRIER;                                                              \
        /* ph7: read aq1(O) */                                                \
        loadA(1, 1);                                                          \
        PHASE_MFMA(1, 0);                                                     \
        BARRIER;                                                              \
        /* ph8: stage A0(O') */                                               \
        if (more) stageA(kO2, 1, 0);                                          \
        PHASE_MFMA(1, 1);                                                     \
        BARRIER;                                                              \
    }

// ===========================================================================
// Projection GEMM: C = A B^T, f16 in, f16 out, ldc-interleaved.
// ===========================================================================
template<bool F16OUT>
__global__ __launch_bounds__(512) void gemm_bt8(
    const f16* __restrict__ A, const f16* __restrict__ B, void* __restrict__ Cv,
    int K, int lda, int ldb, int ldc, float scale, int nbn)
{
    __shared__ f16 sA[2][256 * 64];
    __shared__ f16 sB[2][256 * 64];
    const int tid = threadIdx.x, lane = tid & 63, wid = tid >> 6;
    const int wr = wid >> 2, wc = wid & 3;
    const int cpx = gridDim.x >> 3;
    const int wg = (blockIdx.x & 7) * cpx + (blockIdx.x >> 3);
    const int bm = (wg / nbn) << 8, bn = (wg % nbn) << 8;

    BT8_BODY(0, K >> 6)

#pragma unroll
    for (int i = 0; i < 8; ++i)
#pragma unroll
        for (int j = 0; j < 4; ++j)
#pragma unroll
            for (int r = 0; r < 4; ++r) {
                const int row = bm + wr * 128 + i * 16 + ((lane >> 4) << 2) + r;
                const int col = bn + wc * 64 + j * 16 + (lane & 15);
                if constexpr (F16OUT)
                    ((f16*)Cv)[(size_t)row * ldc + col] = (f16)(acc[i][j][r] * scale);
                else
                    ((float*)Cv)[(size_t)row * ldc + col] = acc[i][j][r] * scale;
            }
}

// ===========================================================================
// QK: bt8 core, S written as plain f16 via LDS-transpose epilogue (verified
// r15: packed 16B stores, full-line coverage).
// ===========================================================================
__global__ __launch_bounds__(512) void gemm_qk(
    const f16* __restrict__ A, const f16* __restrict__ B,
    f16* __restrict__ S, int lda, int ldb)
{
    __shared__ f16 sA[2][256 * 64];
    __shared__ f16 sB[2][256 * 64];
    const int tid = threadIdx.x, lane = tid & 63, wid = tid >> 6;
    const int wr = wid >> 2, wc = wid & 3;
    const int cpx = gridDim.x >> 3;
    const int wg = (blockIdx.x & 7) * cpx + (blockIdx.x >> 3);
    const int bm = (wg >> 4) << 8, bn = (wg & 15) << 8;   // nbn = 16

    BT8_BODY(0, 16)

    // ---- acc -> LDS f16 (sA/sB dead; wr=0 half -> sA, wr=1 half -> sB) ----
    {
        f16* Tb = wr ? (f16*)sB : (f16*)sA;
        const int lg = lane >> 4;
#pragma unroll
        for (int i = 0; i < 8; ++i)
#pragma unroll
            for (int j = 0; j < 4; ++j)
#pragma unroll
                for (int r = 0; r < 4; ++r) {
                    const int rloc = i * 16 + lg * 4 + r;          // 0..127
                    const int col  = wc * 64 + j * 16 + (lane & 15);
                    Tb[rloc * 256 + (col ^ (((rloc >> 2) & 7) << 3))] = (f16)acc[i][j][r];
                }
    }
    BARRIER;
    // ---- LDS -> global: f16x8 per thread-iter, 512B contiguous per row ----
#pragma unroll
    for (int u = 0; u < 16; ++u) {
        const int gi = u * 512 + tid;
        const int row = gi >> 5;                 // 0..255
        const int c0 = (gi & 31) << 3;
        const f16* Tb = (row & 128) ? (const f16*)sB : (const f16*)sA;
        f16x8 v = *(const f16x8*)(Tb + (row & 127) * 256
                                  + (c0 ^ (((row >> 2) & 7) << 3)));
        *(f16x8*)(S + (size_t)(bm + row) * 4096 + bn + c0) = v;
    }
}

// ===========================================================================
// In-place row softmax on f16 S: P = exp(S - m) / (32 l), same location.
// ===========================================================================
__global__ __launch_bounds__(256) void softmax_f16(f16* S)
{
    const int lane = threadIdx.x & 63, wid = threadIdx.x >> 6;
    const int row = blockIdx.x * 4 + wid;
    f16* src = S + (size_t)row * 4096;
    f16x8 v[8];
#pragma unroll
    for (int u = 0; u < 8; ++u) v[u] = *(const f16x8*)(src + u * 512 + lane * 8);
    float m = -1e30f;
#pragma unroll
    for (int u = 0; u < 8; ++u)
#pragma unroll
        for (int e = 0; e < 8; ++e) m = fmaxf(m, (float)v[u][e]);
#pragma unroll
    for (int msk = 1; msk <= 32; msk <<= 1) m = fmaxf(m, __shfl_xor(m, msk));
    float ev[64];
    float s = 0.f;
#pragma unroll
    for (int u = 0; u < 8; ++u)
#pragma unroll
        for (int e = 0; e < 8; ++e) {
            const float x = __expf((float)v[u][e] - m);
            ev[u * 8 + e] = x; s += x;
        }
#pragma unroll
    for (int msk = 1; msk <= 32; msk <<= 1) s += __shfl_xor(s, msk);
    const float inv = 1.0f / (32.0f * s);
#pragma unroll
    for (int u = 0; u < 8; ++u) {
        f16x8 p;
#pragma unroll
        for (int e = 0; e < 8; ++e) p[e] = (f16)(ev[u * 8 + e] * inv);
        *(f16x8*)(src + u * 512 + lane * 8) = p;
    }
}

// ===========================================================================
// PV: bt8 core + split-K=4, plain stores. z=3 -> f32 direct to out;
// z=0..2 -> f16 partials [z][4096][1024].
// ===========================================================================
__global__ __launch_bounds__(512) void gemm_pv8(
    const f16* __restrict__ A, const f16* __restrict__ B, float* __restrict__ Cout,
    f16* __restrict__ Pp, int lda, int ldb)
{
    __shared__ f16 sA[2][256 * 64];
    __shared__ f16 sB[2][256 * 64];
    const int tid = threadIdx.x, lane = tid & 63, wid = tid >> 6;
    const int wr = wid >> 2, wc = wid & 3;
    const int cpx = gridDim.x >> 3;
    const int wg = (blockIdx.x & 7) * cpx + (blockIdx.x >> 3);
    const int bm = (wg >> 2) << 8, bn = (wg & 3) << 8;
    const int z = blockIdx.y;
    const int kbase = z << 10;

    BT8_BODY(kbase, 16)

#pragma unroll
    for (int i = 0; i < 8; ++i)
#pragma unroll
        for (int j = 0; j < 4; ++j)
#pragma unroll
            for (int r = 0; r < 4; ++r) {
                const int row = bm + wr * 128 + i * 16 + ((lane >> 4) << 2) + r;
                const int col = bn + wc * 64 + j * 16 + (lane & 15);
                const float v = acc[i][j][r];
                if (z == 3)
                    Cout[((size_t)row << 10) + col] = v;
                else
                    Pp[(size_t)z * 4194304 + ((size_t)row << 10) + col] = (f16)v;
            }
}

// ===========================================================================
// reduce_pv: out[r][c] = out[r][c](=p3) + p0 + p1 + p2 (flat partials).
// ===========================================================================
__global__ __launch_bounds__(256) void reduce_pv(
    float* __restrict__ Cout, const f16* __restrict__ Pp)
{
    const int i = blockIdx.x * 256 + threadIdx.x;
    const int r = i >> 7;
    const int c = (i & 127) << 3;
    const size_t base = ((size_t)r << 10) + c;
    const f16x8 p0 = *(const f16x8*)(Pp + base);
    const f16x8 p1 = *(const f16x8*)(Pp + base + 4194304);
    const f16x8 p2 = *(const f16x8*)(Pp + base + 8388608);
    float* o = Cout + base;
    float4 o0 = *(float4*)o, o1 = *(float4*)(o + 4);
    o0.x += (float)p0[0] + (float)p1[0] + (float)p2[0];
    o0.y += (float)p0[1] + (float)p1[1] + (float)p2[1];
    o0.z += (float)p0[2] + (float)p1[2] + (float)p2[2];
    o0.w += (float)p0[3] + (float)p1[3] + (float)p2[3];
    o1.x += (float)p0[4] + (float)p1[4] + (float)p2[4];
    o1.y += (float)p0[5] + (float)p1[5] + (float)p2[5];
    o1.z += (float)p0[6] + (float)p1[6] + (float)p2[6];
    o1.w += (float)p0[7] + (float)p1[7] + (float)p2[7];
    *(float4*)o = o0;
    *(float4*)(o + 4) = o1;
}

// ===========================================================================
// 128x128 BT-GEMM, F16IN + PIPE (verified) — used for vT.
// ===========================================================================
__global__ __launch_bounds__(256) void gemm_vt(
    const f16* __restrict__ A, const f16* __restrict__ B, f16* __restrict__ C,
    int K, int lda, int ldb, int ldc)
{
    __shared__ f16 sA[2][128 * 64];
    __shared__ f16 sB[2][128 * 64];
    const int tid = threadIdx.x, lane = tid & 63, wid = tid >> 6;
    const int wr = wid >> 1, wc = wid & 1;
    const int bm = blockIdx.x * 128, bn = blockIdx.y * 128;

    f32x4 acc[4][4] = {};

    auto stage16 = [&](int kt, int bsel) {
        const int rsub = lane >> 3;
        const int csw = ((lane & 7) ^ rsub) << 3;
#pragma unroll
        for (int i = 0; i < 4; ++i) {
            const int rb = (wid * 4 + i) * 8;
            gload16(A + (size_t)(bm + rb + rsub) * lda + kt + csw, &sA[bsel][rb * 64]);
            gload16(B + (size_t)(bn + rb + rsub) * ldb + kt + csw, &sB[bsel][rb * 64]);
        }
    };

    auto compute = [&](int bsel) {
#pragma unroll
        for (int ks = 0; ks < 2; ++ks) {
            const int kk = ks * 32 + (lane >> 4) * 8;
            f16x8 a[4], b[4];
#pragma unroll
            for (int i = 0; i < 4; ++i) {
                const int ra = wr * 64 + i * 16 + (lane & 15);
                a[i] = *(const f16x8*)(&sA[bsel][(ra << 6) + (kk ^ ((ra & 7) << 3))]);
                const int rb2 = wc * 64 + i * 16 + (lane & 15);
                b[i] = *(const f16x8*)(&sB[bsel][(rb2 << 6) + (kk ^ ((rb2 & 7) << 3))]);
            }
#pragma unroll
            for (int i = 0; i < 4; ++i)
#pragma unroll
                for (int j = 0; j < 4; ++j)
                    acc[i][j] = __builtin_amdgcn_mfma_f32_16x16x32_f16(a[i], b[j], acc[i][j], 0, 0, 0);
        }
    };

    stage16(0, 0);
    asm volatile("s_waitcnt vmcnt(0)" ::: "memory");
    __syncthreads();
    const int NT2 = K >> 6;
    for (int t = 0; t < NT2; ++t) {
        if (t + 1 < NT2) stage16((t + 1) << 6, (t + 1) & 1);
        compute(t & 1);
        asm volatile("s_waitcnt vmcnt(0)" ::: "memory");
        __builtin_amdgcn_s_barrier();
    }
#pragma unroll
    for (int i = 0; i < 4; ++i)
#pragma unroll
        for (int j = 0; j < 4; ++j)
#pragma unroll
            for (int r = 0; r < 4; ++r) {
                const int row = bm + wr * 64 + i * 16 + (lane >> 4) * 4 + r;
                const int col = bn + wc * 64 + j * 16 + (lane & 15);
                C[(size_t)row * ldc + col] = (f16)acc[i][j][r];
            }
}

// ---------------------------------------------------------------------------
// Merged upfront convert: x (2097152 x8), Wq (131072 x8), Wk (131072 x8).
// ---------------------------------------------------------------------------
__global__ __launch_bounds__(256) void cvt3(
    const float* __restrict__ x, const float* __restrict__ wq, const float* __restrict__ wk,
    f16* __restrict__ dx, f16* __restrict__ dwq, f16* __restrict__ dwk)
{
    const int i = blockIdx.x * 256 + threadIdx.x;
    const float* s; f16* d; int off;
    if (i < 2097152)      { s = x;  d = dx;  off = i; }
    else if (i < 2228224) { s = wq; d = dwq; off = i - 2097152; }
    else                  { s = wk; d = dwk; off = i - 2228224; }
    const float4 a = ((const float4*)s)[off * 2];
    const float4 b = ((const float4*)s)[off * 2 + 1];
    f16x8 o = { (f16)a.x, (f16)a.y, (f16)a.z, (f16)a.w,
                (f16)b.x, (f16)b.y, (f16)b.z, (f16)b.w };
    ((f16x8*)d)[off] = o;
}

// Merged per-batch convert: x_b (524288 x8) + Wv (131072 x8).
__global__ __launch_bounds__(256) void cvt_batch(
    const float* __restrict__ xb, const float* __restrict__ wv,
    f16* __restrict__ dxb, f16* __restrict__ dwv)
{
    const int i = blockIdx.x * 256 + threadIdx.x;
    const float* s; f16* d; int off;
    if (i < 524288) { s = xb; d = dxb; off = i; }
    else            { s = wv; d = dwv; off = i - 524288; }
    const float4 a = ((const float4*)s)[off * 2];
    const float4 b = ((const float4*)s)[off * 2 + 1];
    f16x8 o = { (f16)a.x, (f16)a.y, (f16)a.z, (f16)a.w,
                (f16)b.x, (f16)b.y, (f16)b.z, (f16)b.w };
    ((f16x8*)d)[off] = o;
}

// ---------------------------------------------------------------------------
// Pipeline: cvt3 -> proj(bt8 x2) -> per batch { QK(f16 S, LDS-transpose) ->
// softmax_f16(in place) -> cvt_batch -> vT(PIPE) -> PV(split-K=4) -> reduce }.
// ws: S/P f16 [4096][4096] @0 (32MB); partials [3][4096][1024] @32MB (24MB);
// vT [1024][4096] @56MB (8MB). Pre-loop: xh@0, wqh/wkh@32MB (dead after proj).
// ---------------------------------------------------------------------------
extern "C" void kernel_launch(void* const* d_in, const int* in_sizes, int n_in,
                              void* d_out, int out_size, void* d_ws, size_t ws_size,
                              hipStream_t stream) {
    const float* x  = (const float*)d_in[0];   // [4,4096,1024]
    const float* Wq = (const float*)d_in[1];   // [1024,1024]
    const float* Wk = (const float*)d_in[2];
    const float* Wv = (const float*)d_in[3];
    float* out = (float*)d_out;                // [4,4096,1024] fp32

    f16*   qk  = (f16*)d_out;                  // q even 1KB-slots, k odd
    f16*   xh  = (f16*)d_ws;                   // 32 MB (transient)
    f16*   wqh = (f16*)((char*)d_ws + (32LL << 20));   // 2 MB (transient)
    f16*   wkh = wqh + 1024LL * 1024;                  // 2 MB (transient)

    f16*   S   = (f16*)d_ws;                                  // 32 MB S/P
    f16*   Pp  = (f16*)((char*)d_ws + (32LL << 20));          // 24 MB partials
    f16*   vTw = (f16*)((char*)d_ws + (56LL << 20));          // 8 MB vT

    cvt3<<<9216, 256, 0, stream>>>(x, Wq, Wk, xh, wqh, wkh);

    gemm_bt8<true><<<256, 512, 0, stream>>>(xh, wqh, qk,        1024, 1024, 1024, 2048, 1.f, 4);
    gemm_bt8<true><<<256, 512, 0, stream>>>(xh, wkh, qk + 1024, 1024, 1024, 1024, 2048, 1.f, 4);

    for (int b = 0; b < 4; ++b) {
        const size_t tb = (size_t)b * 4096;
        f16* xhb = (f16*)(out + tb * 1024);        // dead q_b/k_b region
        f16* wvh = xhb + 4096LL * 1024;            // +8 MB
        // S = q_b k_b^T  (f16, packed stores via LDS transpose)
        gemm_qk<<<256, 512, 0, stream>>>(
            qk + tb * 2048, qk + tb * 2048 + 1024, S, 2048, 2048);
        // P = exp(S - m) / (32 l), in place
        softmax_f16<<<1024, 256, 0, stream>>>(S);
        // cvt x_b + Wv into dead out_b region (one launch)
        cvt_batch<<<2560, 256, 0, stream>>>(x + tb * 1024, Wv, xhb, wvh);
        // vT_b = Wv_h x_b^T -> ws[56:64), ldc 4096
        gemm_vt<<<dim3(8, 32), 256, 0, stream>>>(wvh, xhb, vTw, 1024, 1024, 1024, 4096);
        // att_b = P vT^T: split-K=4, then reduce
        gemm_pv8<<<dim3(64, 4), 512, 0, stream>>>(S, vTw, out + tb * 1024, Pp, 4096, 4096);
        reduce_pv<<<2048, 256, 0, stream>>>(out + tb * 1024, Pp);
    }
}